// Round 5
// baseline (356.134 us; speedup 1.0000x reference)
//
#include <hip/hip_runtime.h>

// ---------------------------------------------------------------------------
// Swin-style windowed MHA block, MI355X/gfx950.
// R5: attn LDS 73.7KB -> 48KB (6 heads x 8KB: V deferred in regs, P consumed
// in 4KB halves, AO overlays). Theory: multi-WG LDS pool ~128KB, so <=64KB
// unlocks 2 blocks/CU. Staging transposed to row-major b128 writes; swizzles
// fixed to vary across colliding lane groups.
// ---------------------------------------------------------------------------

typedef short          s16x8 __attribute__((ext_vector_type(8)));
typedef unsigned short u16x4 __attribute__((ext_vector_type(4)));
typedef unsigned short u16x8 __attribute__((ext_vector_type(8)));
typedef float          f32x4 __attribute__((ext_vector_type(4)));

#define MFMA(A, B, C) __builtin_amdgcn_mfma_f32_16x16x32_bf16((A), (B), (C), 0, 0, 0)

__device__ __forceinline__ unsigned short f2b(float f) {
  unsigned x = __float_as_uint(f);
  x = (x + 0x7FFFu + ((x >> 16) & 1u)) >> 16;   // RNE
  return (unsigned short)x;
}
__device__ __forceinline__ float b2f(unsigned short u) {
  return __uint_as_float(((unsigned)u) << 16);
}

// XOR-chunk swizzles (8-elem = 16B chunks stay contiguous -> b128-aligned).
// swz32: [rows][32] tiles; chunk XOR (t>>1)&3 -> rows 4 apart land on
// different 4-bank slots (row stride 64B = 16 banks).
__device__ __forceinline__ int swz32(int t, int c) {
  return t * 32 + ((((c >> 3) ^ (t >> 1)) & 3) << 3) + (c & 7);
}
// swz64: [rows][64] tiles; row stride 128B = 0 banks -> chunk XOR t&7.
__device__ __forceinline__ int swz64(int t, int c) {
  return t * 64 + ((((c >> 3) ^ t) & 7) << 3) + (c & 7);
}

#define XSTR   200      // xa row stride (elems); 100 dw -> rows spread banks
#define HSZ    4096     // per-head LDS elems (8KB): R0=Q/P/AO, R1=K/Vt
#define QSCALE 0.17677669529663687f

// workspace element offsets (ushort units unless noted)
#define WOFF_QKV   0
#define WOFF_PROJ  110592
#define WOFF_MLP1  147456
#define WOFF_MLP2  221184
#define WOFF_BIASX_BYTES 516096           // float[4096]
#define WOFF_YWIN_BYTES  532480           // ushort[2048*64*192]

// ---------------------------------------------------------------------------
__global__ void prep_kernel(const float* __restrict__ qkv_w,
                            const float* __restrict__ proj_w,
                            const float* __restrict__ mlp1_w,
                            const float* __restrict__ mlp2_w,
                            const float* __restrict__ bias_table,
                            const int*   __restrict__ rel_index,
                            unsigned short* __restrict__ qkv_wb,
                            unsigned short* __restrict__ proj_wb,
                            unsigned short* __restrict__ mlp1_wb,
                            unsigned short* __restrict__ mlp2_wb,
                            float* __restrict__ biasx) {
  int j = blockIdx.x * 256 + threadIdx.x;   // 1024*256 = 262144 jobs exactly
  if (j < 110592) {
    float v = qkv_w[j];
    if (j < 36864) v *= QSCALE;             // fold 1/sqrt(HD) into Q rows
    qkv_wb[j] = f2b(v);
  } else if (j < 147456) {
    proj_wb[j - 110592] = f2b(proj_w[j - 110592]);
  } else if (j < 221184) {
    mlp1_wb[j - 147456] = f2b(mlp1_w[j - 147456]);
  } else if (j < 258048) {
    mlp2_wb[j - 221184] = f2b(mlp2_w[j - 221184]);
  } else {
    int e = j - 258048;                     // 0..4095
    int l = e >> 6, v = e & 63;
    int tm = v >> 4, tn = (v >> 2) & 3, r = v & 3;
    int q = tn * 16 + (l & 15);
    int k = tm * 16 + (l >> 4) * 4 + r;
    biasx[e] = bias_table[rel_index[q * 64 + k]];
  }
}

// ---------------------------------------------------------------------------
__global__ __launch_bounds__(384, 3) void attn_kernel(
    const float* __restrict__ x,
    const unsigned short* __restrict__ qkv_wb, const float* __restrict__ qkv_b,
    const unsigned short* __restrict__ proj_wb, const float* __restrict__ proj_b,
    const float* __restrict__ biasx,
    unsigned short* __restrict__ y_win) {
  __shared__ __align__(16) unsigned short sm[6 * HSZ];  // 49152 B

  const int tid  = threadIdx.x;
  const int lane = tid & 63;
  const int wv   = tid >> 6;      // head index, 0..5
  const int l15  = lane & 15;
  const int lg   = lane >> 4;     // 0..3
  // XCD-aware bijective swizzle: 2048 = 8 XCDs * 256
  const int win  = ((blockIdx.x & 7) << 8) | (blockIdx.x >> 3);
  const int bb   = win >> 8;
  const int wh   = (win >> 4) & 15;
  const int wwi  = win & 15;

  unsigned short* xa = sm;        // [64 tokens][XSTR] bf16 of x-window (dies at B1)
  const float* xwin = x + (size_t)bb * 192 * 16384 + (size_t)(wh * 8) * 128 + wwi * 8;

  // ---- stage x window, transposed jobs: lane = token, 8 channels/lane ----
  // write is a row-major b128 per lane (full-BW LDS), global reads stay 32B-coalesced.
  {
    const int sp = ((lane >> 3) * 128) + (lane & 7);   // spatial offset in window
#pragma unroll
    for (int it = 0; it < 4; ++it) {
      const int chunk = it * 6 + wv;                   // 0..23
      const float* src = xwin + (size_t)(chunk * 8) * 16384 + sp;
      u16x8 pk;
#pragma unroll
      for (int k = 0; k < 8; ++k) pk[k] = f2b(src[(size_t)k * 16384]);
      *(u16x8*)&xa[lane * XSTR + chunk * 8] = pk;
    }
  }
  __syncthreads();  // B0: xa visible to all waves

  unsigned short* hb = sm + wv * HSZ;     // per-head 8KB (wave-private B1..B2)
  unsigned short* R0 = hb;                // Q -> Phalf0 -> Phalf1 -> AO  (4KB)
  unsigned short* R1 = hb + 2048;         // K -> Vt                      (4KB)

  // ---------------- QKV GEMM: [64x192] x [192x32] per head, x3 ----------------
  f32x4 accq[4][2], acck[4][2], accv[4][2];
#pragma unroll
  for (int nt = 0; nt < 2; ++nt) {
    const int o = wv * 32 + nt * 16 + l15;
    const float bq = qkv_b[o] * QSCALE;
    const float bk = qkv_b[192 + o];
    const float bv = qkv_b[384 + o];
#pragma unroll
    for (int m = 0; m < 4; ++m) {
      accq[m][nt] = (f32x4){bq, bq, bq, bq};
      acck[m][nt] = (f32x4){bk, bk, bk, bk};
      accv[m][nt] = (f32x4){bv, bv, bv, bv};
    }
  }
#pragma unroll
  for (int ks = 0; ks < 6; ++ks) {
    const int k0 = ks * 32 + lg * 8;
    s16x8 af[4];
#pragma unroll
    for (int m = 0; m < 4; ++m)
      af[m] = *(const s16x8*)&xa[(m * 16 + l15) * XSTR + k0];
#pragma unroll
    for (int nt = 0; nt < 2; ++nt) {
      const int o = wv * 32 + nt * 16 + l15;
      s16x8 wq  = *(const s16x8*)&qkv_wb[(size_t)o * 192 + k0];
      s16x8 wk  = *(const s16x8*)&qkv_wb[(size_t)(192 + o) * 192 + k0];
      s16x8 wvv = *(const s16x8*)&qkv_wb[(size_t)(384 + o) * 192 + k0];
#pragma unroll
      for (int m = 0; m < 4; ++m) {
        accq[m][nt] = MFMA(af[m], wq , accq[m][nt]);
        acck[m][nt] = MFMA(af[m], wk , acck[m][nt]);
        accv[m][nt] = MFMA(af[m], wvv, accv[m][nt]);
      }
    }
  }
  // ---- residual slice -> registers (then xa is dead) ----
  u16x4 resv[4][2];
#pragma unroll
  for (int m = 0; m < 4; ++m)
#pragma unroll
    for (int nt = 0; nt < 2; ++nt)
#pragma unroll
      for (int r = 0; r < 4; ++r)
        resv[m][nt][r] = xa[(m * 16 + lg * 4 + r) * XSTR + wv * 32 + nt * 16 + l15];
  __syncthreads();  // B1: all xa reads complete -> head regions may overwrite

  // write Q (R0), K (R1); V stays in accv registers until after scores
#pragma unroll
  for (int m = 0; m < 4; ++m)
#pragma unroll
    for (int nt = 0; nt < 2; ++nt) {
      const int d = nt * 16 + l15;
#pragma unroll
      for (int r = 0; r < 4; ++r) {
        const int t = m * 16 + lg * 4 + r;
        R0[swz32(t, d)] = f2b(accq[m][nt][r]);
        R1[swz32(t, d)] = f2b(acck[m][nt][r]);
      }
    }

  // ---------------- scores^T = K . Q^T + bias ----------------
  const float* bxp = biasx + lane * 64;
  s16x8 kf[4], qf[4];
#pragma unroll
  for (int tm = 0; tm < 4; ++tm)
    kf[tm] = *(const s16x8*)&R1[swz32(tm * 16 + l15, lg * 8)];
#pragma unroll
  for (int tn = 0; tn < 4; ++tn)
    qf[tn] = *(const s16x8*)&R0[swz32(tn * 16 + l15, lg * 8)];
  f32x4 sc[4][4];
#pragma unroll
  for (int tm = 0; tm < 4; ++tm)
#pragma unroll
    for (int tn = 0; tn < 4; ++tn) {
      f32x4 bfr = *(const f32x4*)&bxp[tm * 16 + tn * 4];
      sc[tm][tn] = MFMA(kf[tm], qf[tn], bfr);
    }
  // softmax over keys (rows of scores^T): 16 in-lane + shfl_xor 16,32
#pragma unroll
  for (int tn = 0; tn < 4; ++tn) {
    float mx = sc[0][tn][0];
#pragma unroll
    for (int tm = 0; tm < 4; ++tm)
#pragma unroll
      for (int r = 0; r < 4; ++r) mx = fmaxf(mx, sc[tm][tn][r]);
    mx = fmaxf(mx, __shfl_xor(mx, 16));
    mx = fmaxf(mx, __shfl_xor(mx, 32));
    float sum = 0.f;
#pragma unroll
    for (int tm = 0; tm < 4; ++tm)
#pragma unroll
      for (int r = 0; r < 4; ++r) {
        float e = __expf(sc[tm][tn][r] - mx);
        sc[tm][tn][r] = e;
        sum += e;
      }
    sum += __shfl_xor(sum, 16);
    sum += __shfl_xor(sum, 32);
    const float inv = 1.0f / sum;
#pragma unroll
    for (int tm = 0; tm < 4; ++tm)
#pragma unroll
      for (int r = 0; r < 4; ++r) sc[tm][tn][r] *= inv;
  }

  // ---- Vt (from accv regs) over K region; K frags already consumed ----
  // (in-wave DS ops execute in order: these writes cannot pass the kf reads)
#pragma unroll
  for (int m = 0; m < 4; ++m)
#pragma unroll
    for (int nt = 0; nt < 2; ++nt) {
      const int d = nt * 16 + l15;
      u16x4 pv;
      pv[0] = f2b(accv[m][nt][0]); pv[1] = f2b(accv[m][nt][1]);
      pv[2] = f2b(accv[m][nt][2]); pv[3] = f2b(accv[m][nt][3]);
      *(u16x4*)&R1[swz64(d, m * 16 + lg * 4)] = pv;   // Vt[32 d][64 t]
    }

  // ---------------- PV: out[q][d] = P[64x64] . V[64x32], P in 4KB halves ----
  f32x4 oacc[4][2];
#pragma unroll
  for (int m = 0; m < 4; ++m)
#pragma unroll
    for (int nt = 0; nt < 2; ++nt) oacc[m][nt] = (f32x4){0.f, 0.f, 0.f, 0.f};

  // Phalf0: kTok 0..31 (tm 0,1) over Q region (qf consumed)
#pragma unroll
  for (int tm = 0; tm < 2; ++tm)
#pragma unroll
    for (int tn = 0; tn < 4; ++tn) {
      u16x4 pv;
      pv[0] = f2b(sc[tm][tn][0]); pv[1] = f2b(sc[tm][tn][1]);
      pv[2] = f2b(sc[tm][tn][2]); pv[3] = f2b(sc[tm][tn][3]);
      *(u16x4*)&R0[swz32(tn * 16 + l15, tm * 16 + lg * 4)] = pv;
    }
  {
    s16x8 ap[4], bv2[2];
#pragma unroll
    for (int m = 0; m < 4; ++m)
      ap[m] = *(const s16x8*)&R0[swz32(m * 16 + l15, lg * 8)];
#pragma unroll
    for (int nt = 0; nt < 2; ++nt)
      bv2[nt] = *(const s16x8*)&R1[swz64(nt * 16 + l15, lg * 8)];
#pragma unroll
    for (int m = 0; m < 4; ++m)
#pragma unroll
      for (int nt = 0; nt < 2; ++nt)
        oacc[m][nt] = MFMA(ap[m], bv2[nt], oacc[m][nt]);
  }
  // Phalf1: kTok 32..63 (tm 2,3) over same region (ap reads in-order before)
#pragma unroll
  for (int tm = 2; tm < 4; ++tm)
#pragma unroll
    for (int tn = 0; tn < 4; ++tn) {
      u16x4 pv;
      pv[0] = f2b(sc[tm][tn][0]); pv[1] = f2b(sc[tm][tn][1]);
      pv[2] = f2b(sc[tm][tn][2]); pv[3] = f2b(sc[tm][tn][3]);
      *(u16x4*)&R0[swz32(tn * 16 + l15, (tm - 2) * 16 + lg * 4)] = pv;
    }
  {
    s16x8 ap[4], bv2[2];
#pragma unroll
    for (int m = 0; m < 4; ++m)
      ap[m] = *(const s16x8*)&R0[swz32(m * 16 + l15, lg * 8)];
#pragma unroll
    for (int nt = 0; nt < 2; ++nt)
      bv2[nt] = *(const s16x8*)&R1[swz64(nt * 16 + l15, 32 + lg * 8)];
#pragma unroll
    for (int m = 0; m < 4; ++m)
#pragma unroll
      for (int nt = 0; nt < 2; ++nt)
        oacc[m][nt] = MFMA(ap[m], bv2[nt], oacc[m][nt]);
  }

  // ---- attn-out over R0 (Phalf1 consumed; in-order) ----
#pragma unroll
  for (int m = 0; m < 4; ++m)
#pragma unroll
    for (int nt = 0; nt < 2; ++nt) {
      const int d = nt * 16 + l15;
#pragma unroll
      for (int r = 0; r < 4; ++r)
        R0[swz32(m * 16 + lg * 4 + r, d)] = f2b(oacc[m][nt][r]);
    }
  __syncthreads();  // B2: all heads' attn-out visible

  // ---------------- proj (cross-head) + residual ----------------
  f32x4 pj[4][2];
#pragma unroll
  for (int nt = 0; nt < 2; ++nt) {
    const float bp = proj_b[wv * 32 + nt * 16 + l15];
#pragma unroll
    for (int m = 0; m < 4; ++m) pj[m][nt] = (f32x4){bp, bp, bp, bp};
  }
#pragma unroll
  for (int hh = 0; hh < 6; ++hh) {
    const unsigned short* aoh = sm + hh * HSZ;   // head hh's R0 = AO
    s16x8 aa[4];
#pragma unroll
    for (int m = 0; m < 4; ++m)
      aa[m] = *(const s16x8*)&aoh[swz32(m * 16 + l15, lg * 8)];
#pragma unroll
    for (int nt = 0; nt < 2; ++nt) {
      s16x8 wp = *(const s16x8*)&proj_wb[(size_t)(wv * 32 + nt * 16 + l15) * 192 + hh * 32 + lg * 8];
#pragma unroll
      for (int m = 0; m < 4; ++m) pj[m][nt] = MFMA(aa[m], wp, pj[m][nt]);
    }
  }
  __syncthreads();  // B3: all proj reads done -> sm reusable as ybuf

  // y = x + proj scattered into ybuf [64][XSTR]
  unsigned short* ybuf = sm;
#pragma unroll
  for (int m = 0; m < 4; ++m)
#pragma unroll
    for (int nt = 0; nt < 2; ++nt) {
      const int o = wv * 32 + nt * 16 + l15;
#pragma unroll
      for (int r = 0; r < 4; ++r) {
        const int t = m * 16 + lg * 4 + r;
        ybuf[t * XSTR + o] = f2b(pj[m][nt][r] + b2f(resv[m][nt][r]));
      }
    }
  __syncthreads();  // B4
  // coalesced copy ybuf[64][192] -> y_win (contiguous 24.6 KB per window)
  unsigned short* ywp = y_win + (size_t)win * 12288;
#pragma unroll
  for (int it = 0; it < 4; ++it) {
    int job = tid + 384 * it;     // job = t*24 + seg
    int t = job / 24;
    int seg = job - t * 24;
    *(u16x8*)&ywp[(size_t)job * 8] = *(const u16x8*)&ybuf[t * XSTR + seg * 8];
  }
}

// ---------------------------------------------------------------------------
__global__ __launch_bounds__(256) void mlp_kernel(
    const unsigned short* __restrict__ y_win,
    const unsigned short* __restrict__ w1b, const float* __restrict__ b1,
    const unsigned short* __restrict__ w2b, const float* __restrict__ b2,
    float* __restrict__ out) {
  __shared__ __align__(16) unsigned short sm2[2 * 64 * XSTR];  // y_buf + work_buf
  unsigned short* yb = sm2;
  unsigned short* wk = sm2 + 64 * XSTR;

  const int tid  = threadIdx.x;
  const int lane = tid & 63;
  const int wv   = tid >> 6;      // 0..3
  const int l15  = lane & 15;
  const int lg   = lane >> 4;
  const int win  = ((blockIdx.x & 7) << 8) | (blockIdx.x >> 3);
  const int bb   = win >> 8;
  const int wh   = (win >> 4) & 15;
  const int wwi  = win & 15;

  const unsigned short* ywp = y_win + (size_t)win * 12288;
  // ---- stage y tile (fully coalesced) ----
#pragma unroll
  for (int it = 0; it < 6; ++it) {
    int job = tid + 256 * it;     // 1536
    int t = job / 24;
    int seg = job - t * 24;
    *(u16x8*)&yb[t * XSTR + seg * 8] = *(const u16x8*)&ywp[(size_t)job * 8];
  }
  __syncthreads();  // B0

  // ---- GEMM1: h[t][o] = y . w1^T, wave handles paired a/b channel tiles ----
  int ncol[6];
  f32x4 hacc[4][6];
#pragma unroll
  for (int i = 0; i < 6; ++i) {
    int ntile = (i < 3) ? (3 * wv + i) : (9 + 3 * wv + i);  // a-half / b-half pairs
    ncol[i] = ntile * 16 + l15;
    const float bb1 = b1[ncol[i]];
#pragma unroll
    for (int m = 0; m < 4; ++m) hacc[m][i] = (f32x4){bb1, bb1, bb1, bb1};
  }
#pragma unroll
  for (int ks = 0; ks < 6; ++ks) {
    const int k0 = ks * 32 + lg * 8;
    s16x8 af[4];
#pragma unroll
    for (int m = 0; m < 4; ++m)
      af[m] = *(const s16x8*)&yb[(m * 16 + l15) * XSTR + k0];
#pragma unroll
    for (int i = 0; i < 6; ++i) {
      s16x8 wf = *(const s16x8*)&w1b[(size_t)ncol[i] * 192 + k0];
#pragma unroll
      for (int m = 0; m < 4; ++m) hacc[m][i] = MFMA(af[m], wf, hacc[m][i]);
    }
  }
  // ---- GLU: g = a * sigmoid(b), in-register pairing (i, i+3) ----
#pragma unroll
  for (int m = 0; m < 4; ++m)
#pragma unroll
    for (int i = 0; i < 3; ++i) {
#pragma unroll
      for (int r = 0; r < 4; ++r) {
        const float a = hacc[m][i][r];
        const float bg = hacc[m][i + 3][r];
        const float g = a * (1.0f / (1.0f + __expf(-bg)));
        wk[(m * 16 + lg * 4 + r) * XSTR + ncol[i]] = f2b(g);
      }
    }
  __syncthreads();  // B1: g visible

  // ---- GEMM2: m[t][o] = g . w2^T ----
  int ocol[3];
  f32x4 macc[4][3];
#pragma unroll
  for (int i = 0; i < 3; ++i) {
    ocol[i] = (3 * wv + i) * 16 + l15;
    const float bb2 = b2[ocol[i]];
#pragma unroll
    for (int m = 0; m < 4; ++m) macc[m][i] = (f32x4){bb2, bb2, bb2, bb2};
  }
#pragma unroll
  for (int ks = 0; ks < 6; ++ks) {
    const int k0 = ks * 32 + lg * 8;
    s16x8 gf[4];
#pragma unroll
    for (int m = 0; m < 4; ++m)
      gf[m] = *(const s16x8*)&wk[(m * 16 + l15) * XSTR + k0];
#pragma unroll
    for (int i = 0; i < 3; ++i) {
      s16x8 wf = *(const s16x8*)&w2b[(size_t)ocol[i] * 192 + k0];
#pragma unroll
      for (int m = 0; m < 4; ++m) macc[m][i] = MFMA(gf[m], wf, macc[m][i]);
    }
  }
  __syncthreads();  // B2: all g reads done; m may overwrite wk
#pragma unroll
  for (int m = 0; m < 4; ++m)
#pragma unroll
    for (int i = 0; i < 3; ++i)
#pragma unroll
      for (int r = 0; r < 4; ++r)
        wk[(m * 16 + lg * 4 + r) * XSTR + ocol[i]] = f2b(macc[m][i][r]);
  __syncthreads();  // B3: m visible

  // ---- epilogue: out = y + m, BCHW fp32, 32-B runs ----
  float* obase = out + (size_t)bb * 192 * 16384 + (size_t)(wh * 8) * 128 + wwi * 8;
#pragma unroll
  for (int it = 0; it < 6; ++it) {
    int job = tid + 256 * it;     // job = c + 192*i (c fast -> conflict-free LDS)
    int i = job / 192;
    int c = job - i * 192;
    float vals[8];
#pragma unroll
    for (int j = 0; j < 8; ++j) {
      const int t = i * 8 + j;
      vals[j] = b2f(yb[t * XSTR + c]) + b2f(wk[t * XSTR + c]);
    }
    float* dst = obase + (size_t)c * 16384 + i * 128;
    f32x4 o0 = {vals[0], vals[1], vals[2], vals[3]};
    f32x4 o1 = {vals[4], vals[5], vals[6], vals[7]};
    *(f32x4*)dst = o0;
    *(f32x4*)(dst + 4) = o1;
  }
}

// ---------------------------------------------------------------------------
extern "C" void kernel_launch(void* const* d_in, const int* in_sizes, int n_in,
                              void* d_out, int out_size, void* d_ws, size_t ws_size,
                              hipStream_t stream) {
  (void)in_sizes; (void)n_in; (void)out_size; (void)ws_size;
  const float* x          = (const float*)d_in[0];
  const float* qkv_w      = (const float*)d_in[1];
  const float* qkv_b      = (const float*)d_in[2];
  const float* proj_w     = (const float*)d_in[3];
  const float* proj_b     = (const float*)d_in[4];
  const float* mlp1_w     = (const float*)d_in[5];
  const float* mlp1_b     = (const float*)d_in[6];
  const float* mlp2_w     = (const float*)d_in[7];
  const float* mlp2_b     = (const float*)d_in[8];
  const float* bias_table = (const float*)d_in[9];
  const int*   rel_index  = (const int*)d_in[10];
  float* out = (float*)d_out;

  char* ws = (char*)d_ws;
  unsigned short* qkv_wb  = (unsigned short*)ws + WOFF_QKV;
  unsigned short* proj_wb = (unsigned short*)ws + WOFF_PROJ;
  unsigned short* mlp1_wb = (unsigned short*)ws + WOFF_MLP1;
  unsigned short* mlp2_wb = (unsigned short*)ws + WOFF_MLP2;
  float*          biasx   = (float*)(ws + WOFF_BIASX_BYTES);
  unsigned short* y_win   = (unsigned short*)(ws + WOFF_YWIN_BYTES);

  hipLaunchKernelGGL(prep_kernel, dim3(1024), dim3(256), 0, stream,
                     qkv_w, proj_w, mlp1_w, mlp2_w, bias_table, rel_index,
                     qkv_wb, proj_wb, mlp1_wb, mlp2_wb, biasx);
  hipLaunchKernelGGL(attn_kernel, dim3(2048), dim3(384), 0, stream,
                     x, qkv_wb, qkv_b, proj_wb, proj_b, biasx, y_win);
  hipLaunchKernelGGL(mlp_kernel, dim3(2048), dim3(256), 0, stream,
                     y_win, mlp1_wb, mlp1_b, mlp2_wb, mlp2_b, out);
}

// Round 6
// 243.324 us; speedup vs baseline: 1.4636x; 1.4636x over previous
//
#include <hip/hip_runtime.h>

// ---------------------------------------------------------------------------
// Swin-style windowed MHA block, MI355X/gfx950.
// R6: 768-thread attn block = 12 waves = 2 windows x 6 heads, guaranteeing
// 12 waves/CU co-residency (intra-block). Register diet: nt-split QKV,
// bf16 V-regs, no resv. Head LDS regions disjoint from xa -> 3 barriers.
// LDS 149.5KB/block. Coalesced (R4) staging; verified (R5) swizzles.
// ---------------------------------------------------------------------------

typedef short          s16x8 __attribute__((ext_vector_type(8)));
typedef unsigned short u16x4 __attribute__((ext_vector_type(4)));
typedef unsigned short u16x8 __attribute__((ext_vector_type(8)));
typedef float          f32x4 __attribute__((ext_vector_type(4)));

#define MFMA(A, B, C) __builtin_amdgcn_mfma_f32_16x16x32_bf16((A), (B), (C), 0, 0, 0)

__device__ __forceinline__ unsigned short f2b(float f) {
  unsigned x = __float_as_uint(f);
  x = (x + 0x7FFFu + ((x >> 16) & 1u)) >> 16;   // RNE
  return (unsigned short)x;
}
__device__ __forceinline__ float b2f(unsigned short u) {
  return __uint_as_float(((unsigned)u) << 16);
}

// XOR-chunk swizzles (8-elem = 16B chunks stay contiguous -> b128-aligned).
__device__ __forceinline__ int swz32(int t, int c) {   // [rows][32] tiles
  return t * 32 + ((((c >> 3) ^ (t >> 1)) & 3) << 3) + (c & 7);
}
__device__ __forceinline__ int swz64(int t, int c) {   // [rows][64] tiles
  return t * 64 + ((((c >> 3) ^ t) & 7) << 3) + (c & 7);
}

#define XSTR   200      // xa row stride (elems)
#define WSLOT  37376    // elems/window: xa 12800 + 6 heads * 4096
#define QSCALE 0.17677669529663687f

// workspace element offsets (ushort units unless noted)
#define WOFF_QKV   0
#define WOFF_PROJ  110592
#define WOFF_MLP1  147456
#define WOFF_MLP2  221184
#define WOFF_BIASX_BYTES 516096           // float[4096]
#define WOFF_YWIN_BYTES  532480           // ushort[2048*64*192]

// ---------------------------------------------------------------------------
__global__ void prep_kernel(const float* __restrict__ qkv_w,
                            const float* __restrict__ proj_w,
                            const float* __restrict__ mlp1_w,
                            const float* __restrict__ mlp2_w,
                            const float* __restrict__ bias_table,
                            const int*   __restrict__ rel_index,
                            unsigned short* __restrict__ qkv_wb,
                            unsigned short* __restrict__ proj_wb,
                            unsigned short* __restrict__ mlp1_wb,
                            unsigned short* __restrict__ mlp2_wb,
                            float* __restrict__ biasx) {
  int j = blockIdx.x * 256 + threadIdx.x;   // 1024*256 = 262144 jobs exactly
  if (j < 110592) {
    float v = qkv_w[j];
    if (j < 36864) v *= QSCALE;             // fold 1/sqrt(HD) into Q rows
    qkv_wb[j] = f2b(v);
  } else if (j < 147456) {
    proj_wb[j - 110592] = f2b(proj_w[j - 110592]);
  } else if (j < 221184) {
    mlp1_wb[j - 147456] = f2b(mlp1_w[j - 147456]);
  } else if (j < 258048) {
    mlp2_wb[j - 221184] = f2b(mlp2_w[j - 221184]);
  } else {
    int e = j - 258048;                     // 0..4095
    int l = e >> 6, v = e & 63;
    int tm = v >> 4, tn = (v >> 2) & 3, r = v & 3;
    int q = tn * 16 + (l & 15);
    int k = tm * 16 + (l >> 4) * 4 + r;
    biasx[e] = bias_table[rel_index[q * 64 + k]];
  }
}

// ---------------------------------------------------------------------------
__global__ __launch_bounds__(768, 3) void attn_kernel(
    const float* __restrict__ x,
    const unsigned short* __restrict__ qkv_wb, const float* __restrict__ qkv_b,
    const unsigned short* __restrict__ proj_wb, const float* __restrict__ proj_b,
    const float* __restrict__ biasx,
    unsigned short* __restrict__ y_win) {
  __shared__ __align__(16) unsigned short sm[2 * WSLOT];  // 149504 B

  const int tid  = threadIdx.x;
  const int lane = tid & 63;
  const int wv   = tid >> 6;          // 0..11
  const int wid  = (wv >= 6) ? 1 : 0; // window within block
  const int hd   = wv - wid * 6;      // head 0..5
  const int l15  = lane & 15;
  const int lg   = lane >> 4;         // 0..3
  // XCD-aware bijective swizzle over 1024 blocks (1024%8==0)
  const int pair = ((blockIdx.x & 7) << 7) | (blockIdx.x >> 3);
  const int wins0 = pair * 2;

  // per-window x base pointers
  const float* xwb[2];
#pragma unroll
  for (int wi = 0; wi < 2; ++wi) {
    const int w = wins0 + wi;
    xwb[wi] = x + (size_t)(w >> 8) * 192 * 16384
                + (size_t)(((w >> 4) & 15) * 8) * 128 + (w & 15) * 8;
  }

  // ---- stage both windows (coalesced 32B reads, as R4) ----
#pragma unroll
  for (int it = 0; it < 4; ++it) {
    int job = tid + 768 * it;         // 0..3071
    int wi = job / 1536;
    int j = job - wi * 1536;
    int c = j >> 3, i = j & 7;
    const float* src = xwb[wi] + (size_t)c * 16384 + i * 128;
    f32x4 v0 = *(const f32x4*)(src);
    f32x4 v1 = *(const f32x4*)(src + 4);
    unsigned short* dst = &sm[wi * WSLOT + (i * 8) * XSTR + c];
    dst[0 * XSTR] = f2b(v0[0]); dst[1 * XSTR] = f2b(v0[1]);
    dst[2 * XSTR] = f2b(v0[2]); dst[3 * XSTR] = f2b(v0[3]);
    dst[4 * XSTR] = f2b(v1[0]); dst[5 * XSTR] = f2b(v1[1]);
    dst[6 * XSTR] = f2b(v1[2]); dst[7 * XSTR] = f2b(v1[3]);
  }
  __syncthreads();  // B0: both xa visible

  unsigned short* xa = sm + wid * WSLOT;                 // [64][XSTR]
  unsigned short* hb = xa + 12800 + hd * 4096;           // 8KB head region
  unsigned short* R0 = hb;            // Q -> Phalf -> AO (4KB)
  unsigned short* R1 = hb + 2048;     // K -> Vt          (4KB)

  // ---------------- QKV, nt-split (acc peak 64 regs) ----------------
  f32x4 accv[4][2];
#pragma unroll
  for (int nt = 0; nt < 2; ++nt) {
    const float bv = qkv_b[384 + hd * 32 + nt * 16 + l15];
#pragma unroll
    for (int m = 0; m < 4; ++m) accv[m][nt] = (f32x4){bv, bv, bv, bv};
  }
#pragma unroll
  for (int nt = 0; nt < 2; ++nt) {
    const int o = hd * 32 + nt * 16 + l15;
    const float bq = qkv_b[o] * QSCALE;
    const float bk = qkv_b[192 + o];
    f32x4 accq[4], acck[4];
#pragma unroll
    for (int m = 0; m < 4; ++m) {
      accq[m] = (f32x4){bq, bq, bq, bq};
      acck[m] = (f32x4){bk, bk, bk, bk};
    }
#pragma unroll
    for (int ks = 0; ks < 6; ++ks) {
      const int k0 = ks * 32 + lg * 8;
      s16x8 af[4];
#pragma unroll
      for (int m = 0; m < 4; ++m)
        af[m] = *(const s16x8*)&xa[(m * 16 + l15) * XSTR + k0];
      s16x8 wq  = *(const s16x8*)&qkv_wb[(size_t)o * 192 + k0];
      s16x8 wk  = *(const s16x8*)&qkv_wb[(size_t)(192 + o) * 192 + k0];
      s16x8 wvv = *(const s16x8*)&qkv_wb[(size_t)(384 + o) * 192 + k0];
#pragma unroll
      for (int m = 0; m < 4; ++m) {
        accq[m] = MFMA(af[m], wq, accq[m]);
        acck[m] = MFMA(af[m], wk, acck[m]);
        accv[m][nt] = MFMA(af[m], wvv, accv[m][nt]);
      }
    }
    // write Q,K column-halves (head region disjoint from xa: no barrier)
#pragma unroll
    for (int m = 0; m < 4; ++m)
#pragma unroll
      for (int r = 0; r < 4; ++r) {
        const int t = m * 16 + lg * 4 + r;
        const int d = nt * 16 + l15;
        R0[swz32(t, d)] = f2b(accq[m][r]);
        R1[swz32(t, d)] = f2b(acck[m][r]);
      }
  }
  // V -> bf16 regs (frees 32 f32 accs, keeps 16)
  u16x4 vreg[4][2];
#pragma unroll
  for (int m = 0; m < 4; ++m)
#pragma unroll
    for (int nt = 0; nt < 2; ++nt) {
      vreg[m][nt][0] = f2b(accv[m][nt][0]); vreg[m][nt][1] = f2b(accv[m][nt][1]);
      vreg[m][nt][2] = f2b(accv[m][nt][2]); vreg[m][nt][3] = f2b(accv[m][nt][3]);
    }

  // ---------------- scores^T = K . Q^T + bias ----------------
  const float* bxp = biasx + lane * 64;
  s16x8 kf[4], qf[4];
#pragma unroll
  for (int tm = 0; tm < 4; ++tm)
    kf[tm] = *(const s16x8*)&R1[swz32(tm * 16 + l15, lg * 8)];
#pragma unroll
  for (int tn = 0; tn < 4; ++tn)
    qf[tn] = *(const s16x8*)&R0[swz32(tn * 16 + l15, lg * 8)];
  // Vt over K (after kf reads; in-wave DS order)
#pragma unroll
  for (int m = 0; m < 4; ++m)
#pragma unroll
    for (int nt = 0; nt < 2; ++nt)
      *(u16x4*)&R1[swz64(nt * 16 + l15, m * 16 + lg * 4)] = vreg[m][nt];

  f32x4 sc[4][4];
#pragma unroll
  for (int tm = 0; tm < 4; ++tm)
#pragma unroll
    for (int tn = 0; tn < 4; ++tn) {
      f32x4 bfr = *(const f32x4*)&bxp[tm * 16 + tn * 4];
      sc[tm][tn] = MFMA(kf[tm], qf[tn], bfr);
    }
  // softmax over keys: 16 in-lane + shfl_xor 16,32
#pragma unroll
  for (int tn = 0; tn < 4; ++tn) {
    float mx = sc[0][tn][0];
#pragma unroll
    for (int tm = 0; tm < 4; ++tm)
#pragma unroll
      for (int r = 0; r < 4; ++r) mx = fmaxf(mx, sc[tm][tn][r]);
    mx = fmaxf(mx, __shfl_xor(mx, 16));
    mx = fmaxf(mx, __shfl_xor(mx, 32));
    float sum = 0.f;
#pragma unroll
    for (int tm = 0; tm < 4; ++tm)
#pragma unroll
      for (int r = 0; r < 4; ++r) {
        float e = __expf(sc[tm][tn][r] - mx);
        sc[tm][tn][r] = e;
        sum += e;
      }
    sum += __shfl_xor(sum, 16);
    sum += __shfl_xor(sum, 32);
    const float inv = 1.0f / sum;
#pragma unroll
    for (int tm = 0; tm < 4; ++tm)
#pragma unroll
      for (int r = 0; r < 4; ++r) sc[tm][tn][r] *= inv;
  }

  // ---------------- PV in two k-halves over R0 ----------------
  f32x4 oacc[4][2];
#pragma unroll
  for (int m = 0; m < 4; ++m)
#pragma unroll
    for (int nt = 0; nt < 2; ++nt) oacc[m][nt] = (f32x4){0.f, 0.f, 0.f, 0.f};
#pragma unroll
  for (int half = 0; half < 2; ++half) {
#pragma unroll
    for (int tm = 0; tm < 2; ++tm)
#pragma unroll
      for (int tn = 0; tn < 4; ++tn) {
        u16x4 pv;
        pv[0] = f2b(sc[half * 2 + tm][tn][0]); pv[1] = f2b(sc[half * 2 + tm][tn][1]);
        pv[2] = f2b(sc[half * 2 + tm][tn][2]); pv[3] = f2b(sc[half * 2 + tm][tn][3]);
        *(u16x4*)&R0[swz32(tn * 16 + l15, tm * 16 + lg * 4)] = pv;
      }
    s16x8 ap[4], bv2[2];
#pragma unroll
    for (int m = 0; m < 4; ++m)
      ap[m] = *(const s16x8*)&R0[swz32(m * 16 + l15, lg * 8)];
#pragma unroll
    for (int nt = 0; nt < 2; ++nt)
      bv2[nt] = *(const s16x8*)&R1[swz64(nt * 16 + l15, half * 32 + lg * 8)];
#pragma unroll
    for (int m = 0; m < 4; ++m)
#pragma unroll
      for (int nt = 0; nt < 2; ++nt)
        oacc[m][nt] = MFMA(ap[m], bv2[nt], oacc[m][nt]);
  }
  // AO over R0 (ap consumed; in-wave order)
#pragma unroll
  for (int m = 0; m < 4; ++m)
#pragma unroll
    for (int nt = 0; nt < 2; ++nt) {
      const int d = nt * 16 + l15;
#pragma unroll
      for (int r = 0; r < 4; ++r)
        R0[swz32(m * 16 + lg * 4 + r, d)] = f2b(oacc[m][nt][r]);
    }
  __syncthreads();  // B2: all heads' AO visible

  // ---------------- proj (cross-head) + residual RMW into xa ----------------
  f32x4 pj[4][2];
#pragma unroll
  for (int nt = 0; nt < 2; ++nt) {
    const float bp = proj_b[hd * 32 + nt * 16 + l15];
#pragma unroll
    for (int m = 0; m < 4; ++m) pj[m][nt] = (f32x4){bp, bp, bp, bp};
  }
#pragma unroll
  for (int hh = 0; hh < 6; ++hh) {
    const unsigned short* aoh = xa + 12800 + hh * 4096;   // head hh's R0 = AO
    s16x8 aa[4];
#pragma unroll
    for (int m = 0; m < 4; ++m)
      aa[m] = *(const s16x8*)&aoh[swz32(m * 16 + l15, lg * 8)];
#pragma unroll
    for (int nt = 0; nt < 2; ++nt) {
      s16x8 wp = *(const s16x8*)&proj_wb[(size_t)(hd * 32 + nt * 16 + l15) * 192 + hh * 32 + lg * 8];
#pragma unroll
      for (int m = 0; m < 4; ++m) pj[m][nt] = MFMA(aa[m], wp, pj[m][nt]);
    }
  }
  // y = x + proj: RMW wave-private (t,o) cells of untouched xa
#pragma unroll
  for (int m = 0; m < 4; ++m)
#pragma unroll
    for (int nt = 0; nt < 2; ++nt) {
      const int o = hd * 32 + nt * 16 + l15;
#pragma unroll
      for (int r = 0; r < 4; ++r) {
        const int t = m * 16 + lg * 4 + r;
        xa[t * XSTR + o] = f2b(pj[m][nt][r] + b2f(xa[t * XSTR + o]));
      }
    }
  __syncthreads();  // B3: y complete for both windows
  // coalesced copy both windows' y -> y_win
#pragma unroll
  for (int it = 0; it < 4; ++it) {
    int job = tid + 768 * it;
    int wi = job / 1536;
    int j = job - wi * 1536;
    int t = j / 24;
    int seg = j - t * 24;
    unsigned short* ywp = y_win + (size_t)(wins0 + wi) * 12288;
    *(u16x8*)&ywp[(size_t)j * 8] = *(const u16x8*)&sm[wi * WSLOT + t * XSTR + seg * 8];
  }
}

// ---------------------------------------------------------------------------
__global__ __launch_bounds__(256, 4) void mlp_kernel(
    const unsigned short* __restrict__ y_win,
    const unsigned short* __restrict__ w1b, const float* __restrict__ b1,
    const unsigned short* __restrict__ w2b, const float* __restrict__ b2,
    float* __restrict__ out) {
  __shared__ __align__(16) unsigned short sm2[2 * 64 * XSTR];  // y_buf + work_buf
  unsigned short* yb = sm2;
  unsigned short* wk = sm2 + 64 * XSTR;

  const int tid  = threadIdx.x;
  const int lane = tid & 63;
  const int wv   = tid >> 6;      // 0..3
  const int l15  = lane & 15;
  const int lg   = lane >> 4;
  const int win  = ((blockIdx.x & 7) << 8) | (blockIdx.x >> 3);
  const int bb   = win >> 8;
  const int wh   = (win >> 4) & 15;
  const int wwi  = win & 15;

  const unsigned short* ywp = y_win + (size_t)win * 12288;
  // ---- stage y tile (fully coalesced) ----
#pragma unroll
  for (int it = 0; it < 6; ++it) {
    int job = tid + 256 * it;     // 1536
    int t = job / 24;
    int seg = job - t * 24;
    *(u16x8*)&yb[t * XSTR + seg * 8] = *(const u16x8*)&ywp[(size_t)job * 8];
  }
  __syncthreads();  // B0

  // ---- GEMM1 + GLU, one a/b pair at a time (acc peak 32 regs) ----
#pragma unroll
  for (int i = 0; i < 3; ++i) {
    const int na = (3 * wv + i) * 16 + l15;   // a column (0..191)
    const int nb = na + 192;                  // paired b column
    f32x4 aacc[4], bacc[4];
    const float ba = b1[na], bbv = b1[nb];
#pragma unroll
    for (int m = 0; m < 4; ++m) {
      aacc[m] = (f32x4){ba, ba, ba, ba};
      bacc[m] = (f32x4){bbv, bbv, bbv, bbv};
    }
#pragma unroll
    for (int ks = 0; ks < 6; ++ks) {
      const int k0 = ks * 32 + lg * 8;
      s16x8 af[4];
#pragma unroll
      for (int m = 0; m < 4; ++m)
        af[m] = *(const s16x8*)&yb[(m * 16 + l15) * XSTR + k0];
      s16x8 wa = *(const s16x8*)&w1b[(size_t)na * 192 + k0];
      s16x8 wb = *(const s16x8*)&w1b[(size_t)nb * 192 + k0];
#pragma unroll
      for (int m = 0; m < 4; ++m) {
        aacc[m] = MFMA(af[m], wa, aacc[m]);
        bacc[m] = MFMA(af[m], wb, bacc[m]);
      }
    }
#pragma unroll
    for (int m = 0; m < 4; ++m)
#pragma unroll
      for (int r = 0; r < 4; ++r) {
        const float g = aacc[m][r] * (1.0f / (1.0f + __expf(-bacc[m][r])));
        wk[(m * 16 + lg * 4 + r) * XSTR + na] = f2b(g);
      }
  }
  __syncthreads();  // B1: g visible

  // ---- GEMM2: m[t][o] = g . w2^T ----
  int ocol[3];
  f32x4 macc[4][3];
#pragma unroll
  for (int i = 0; i < 3; ++i) {
    ocol[i] = (3 * wv + i) * 16 + l15;
    const float bb2 = b2[ocol[i]];
#pragma unroll
    for (int m = 0; m < 4; ++m) macc[m][i] = (f32x4){bb2, bb2, bb2, bb2};
  }
#pragma unroll
  for (int ks = 0; ks < 6; ++ks) {
    const int k0 = ks * 32 + lg * 8;
    s16x8 gf[4];
#pragma unroll
    for (int m = 0; m < 4; ++m)
      gf[m] = *(const s16x8*)&wk[(m * 16 + l15) * XSTR + k0];
#pragma unroll
    for (int i = 0; i < 3; ++i) {
      s16x8 wf = *(const s16x8*)&w2b[(size_t)ocol[i] * 192 + k0];
#pragma unroll
      for (int m = 0; m < 4; ++m) macc[m][i] = MFMA(gf[m], wf, macc[m][i]);
    }
  }
  __syncthreads();  // B2: all g reads done; m may overwrite wk
#pragma unroll
  for (int m = 0; m < 4; ++m)
#pragma unroll
    for (int i = 0; i < 3; ++i)
#pragma unroll
      for (int r = 0; r < 4; ++r)
        wk[(m * 16 + lg * 4 + r) * XSTR + ocol[i]] = f2b(macc[m][i][r]);
  __syncthreads();  // B3: m visible

  // ---- epilogue: out = y + m, BCHW fp32, 32-B runs ----
  float* obase = out + (size_t)bb * 192 * 16384 + (size_t)(wh * 8) * 128 + wwi * 8;
#pragma unroll
  for (int it = 0; it < 6; ++it) {
    int job = tid + 256 * it;     // job = c + 192*i (c fast -> conflict-free LDS)
    int i = job / 192;
    int c = job - i * 192;
    float vals[8];
#pragma unroll
    for (int j = 0; j < 8; ++j) {
      const int t = i * 8 + j;
      vals[j] = b2f(yb[t * XSTR + c]) + b2f(wk[t * XSTR + c]);
    }
    float* dst = obase + (size_t)c * 16384 + i * 128;
    f32x4 o0 = {vals[0], vals[1], vals[2], vals[3]};
    f32x4 o1 = {vals[4], vals[5], vals[6], vals[7]};
    *(f32x4*)dst = o0;
    *(f32x4*)(dst + 4) = o1;
  }
}

// ---------------------------------------------------------------------------
extern "C" void kernel_launch(void* const* d_in, const int* in_sizes, int n_in,
                              void* d_out, int out_size, void* d_ws, size_t ws_size,
                              hipStream_t stream) {
  (void)in_sizes; (void)n_in; (void)out_size; (void)ws_size;
  const float* x          = (const float*)d_in[0];
  const float* qkv_w      = (const float*)d_in[1];
  const float* qkv_b      = (const float*)d_in[2];
  const float* proj_w     = (const float*)d_in[3];
  const float* proj_b     = (const float*)d_in[4];
  const float* mlp1_w     = (const float*)d_in[5];
  const float* mlp1_b     = (const float*)d_in[6];
  const float* mlp2_w     = (const float*)d_in[7];
  const float* mlp2_b     = (const float*)d_in[8];
  const float* bias_table = (const float*)d_in[9];
  const int*   rel_index  = (const int*)d_in[10];
  float* out = (float*)d_out;

  char* ws = (char*)d_ws;
  unsigned short* qkv_wb  = (unsigned short*)ws + WOFF_QKV;
  unsigned short* proj_wb = (unsigned short*)ws + WOFF_PROJ;
  unsigned short* mlp1_wb = (unsigned short*)ws + WOFF_MLP1;
  unsigned short* mlp2_wb = (unsigned short*)ws + WOFF_MLP2;
  float*          biasx   = (float*)(ws + WOFF_BIASX_BYTES);
  unsigned short* y_win   = (unsigned short*)(ws + WOFF_YWIN_BYTES);

  hipLaunchKernelGGL(prep_kernel, dim3(1024), dim3(256), 0, stream,
                     qkv_w, proj_w, mlp1_w, mlp2_w, bias_table, rel_index,
                     qkv_wb, proj_wb, mlp1_wb, mlp2_wb, biasx);
  hipLaunchKernelGGL(attn_kernel, dim3(1024), dim3(768), 0, stream,
                     x, qkv_wb, qkv_b, proj_wb, proj_b, biasx, y_win);
  hipLaunchKernelGGL(mlp_kernel, dim3(2048), dim3(256), 0, stream,
                     y_win, mlp1_wb, mlp1_b, mlp2_wb, mlp2_b, out);
}

// Round 8
// 236.135 us; speedup vs baseline: 1.5082x; 1.0304x over previous
//
#include <hip/hip_runtime.h>

// ---------------------------------------------------------------------------
// Swin-style windowed MHA block, MI355X/gfx950.
// R8 = R7 with the xa-swizzle bijectivity fix: chunk' = (c>>3) ^ ((t>>3)&7)
// (NO outer &7 -- R7's version dropped chunk high bits and collided channels
// 0/64/128). Operand-swapped MFMAs (Q^T/K^T, out^T, proj^T) keep all LDS
// C-stores vectorized; 768-thread block = 12 waves = 2 windows.
// ---------------------------------------------------------------------------

typedef short          s16x8 __attribute__((ext_vector_type(8)));
typedef unsigned short u16x4 __attribute__((ext_vector_type(4)));
typedef unsigned short u16x8 __attribute__((ext_vector_type(8)));
typedef float          f32x4 __attribute__((ext_vector_type(4)));

#define MFMA(A, B, C) __builtin_amdgcn_mfma_f32_16x16x32_bf16((A), (B), (C), 0, 0, 0)

__device__ __forceinline__ unsigned short f2b(float f) {
  unsigned x = __float_as_uint(f);
  x = (x + 0x7FFFu + ((x >> 16) & 1u)) >> 16;   // RNE
  return (unsigned short)x;
}
__device__ __forceinline__ float b2f(unsigned short u) {
  return __uint_as_float(((unsigned)u) << 16);
}

// [64][32] tiles (Q,K,P-half,AO): 16B-chunk XOR keyed on (t>>1)&3
__device__ __forceinline__ int swz32(int t, int c) {
  return t * 32 + ((((c >> 3) ^ (t >> 1)) & 3) << 3) + (c & 7);
}
// Vt [32][64]: chunk XOR keyed on (d + (d>>3)) & 7
__device__ __forceinline__ int swzV(int d, int t) {
  return d * 64 + ((((t >> 3) ^ (d + (d >> 3))) & 7) << 3) + (t & 7);
}

#define XSTR   200      // xa row stride (elems)
// xa [64][XSTR]: BIJECTIVE chunk XOR -- key is 3 bits, chunk keeps ALL bits.
__device__ __forceinline__ int xsw(int t, int c) {
  return t * XSTR + ((((c >> 3) ^ ((t >> 3) & 7))) << 3) + (c & 7);
}

#define WSLOT  37376    // elems/window: xa 12800 + 6 heads * 4096
#define QSCALE 0.17677669529663687f

// workspace element offsets (ushort units unless noted)
#define WOFF_QKV   0
#define WOFF_PROJ  110592
#define WOFF_MLP1  147456
#define WOFF_MLP2  221184
#define WOFF_BIASX_BYTES 516096           // float[4096]
#define WOFF_YWIN_BYTES  532480           // ushort[2048*64*192]

// ---------------------------------------------------------------------------
__global__ void prep_kernel(const float* __restrict__ qkv_w,
                            const float* __restrict__ proj_w,
                            const float* __restrict__ mlp1_w,
                            const float* __restrict__ mlp2_w,
                            const float* __restrict__ bias_table,
                            const int*   __restrict__ rel_index,
                            unsigned short* __restrict__ qkv_wb,
                            unsigned short* __restrict__ proj_wb,
                            unsigned short* __restrict__ mlp1_wb,
                            unsigned short* __restrict__ mlp2_wb,
                            float* __restrict__ biasx) {
  int j = blockIdx.x * 256 + threadIdx.x;   // 1024*256 = 262144 jobs exactly
  if (j < 110592) {
    float v = qkv_w[j];
    if (j < 36864) v *= QSCALE;             // fold 1/sqrt(HD) into Q rows
    qkv_wb[j] = f2b(v);
  } else if (j < 147456) {
    proj_wb[j - 110592] = f2b(proj_w[j - 110592]);
  } else if (j < 221184) {
    mlp1_wb[j - 147456] = f2b(mlp1_w[j - 147456]);
  } else if (j < 258048) {
    mlp2_wb[j - 221184] = f2b(mlp2_w[j - 221184]);
  } else {
    int e = j - 258048;                     // 0..4095
    int l = e >> 6, v = e & 63;
    int tm = v >> 4, tn = (v >> 2) & 3, r = v & 3;
    int q = tn * 16 + (l & 15);
    int k = tm * 16 + (l >> 4) * 4 + r;
    biasx[e] = bias_table[rel_index[q * 64 + k]];
  }
}

// ---------------------------------------------------------------------------
__global__ __launch_bounds__(768, 3) void attn_kernel(
    const float* __restrict__ x,
    const unsigned short* __restrict__ qkv_wb, const float* __restrict__ qkv_b,
    const unsigned short* __restrict__ proj_wb, const float* __restrict__ proj_b,
    const float* __restrict__ biasx,
    unsigned short* __restrict__ y_win) {
  __shared__ __align__(16) unsigned short sm[2 * WSLOT];  // 149504 B

  const int tid  = threadIdx.x;
  const int lane = tid & 63;
  const int wv   = tid >> 6;          // 0..11
  const int wid  = (wv >= 6) ? 1 : 0; // window within block
  const int hd   = wv - wid * 6;      // head 0..5
  const int l15  = lane & 15;
  const int lg   = lane >> 4;         // 0..3
  const int pair = ((blockIdx.x & 7) << 7) | (blockIdx.x >> 3);  // XCD swizzle
  const int wins0 = pair * 2;

  const float* xwb[2];
#pragma unroll
  for (int wi = 0; wi < 2; ++wi) {
    const int w = wins0 + wi;
    xwb[wi] = x + (size_t)(w >> 8) * 192 * 16384
                + (size_t)(((w >> 4) & 15) * 8) * 128 + (w & 15) * 8;
  }

  // ---- stage both windows: coalesced 32B global reads, swizzled LDS scatter ----
#pragma unroll
  for (int it = 0; it < 4; ++it) {
    int job = tid + 768 * it;         // 0..3071
    int wi = job / 1536;
    int j = job - wi * 1536;
    int c = j >> 3, i = j & 7;        // channel, spatial-row-group
    const float* src = xwb[wi] + (size_t)c * 16384 + i * 128;
    f32x4 v0 = *(const f32x4*)(src);
    f32x4 v1 = *(const f32x4*)(src + 4);
    // rows t = i*8+r => (t>>3)&7 == i; bijective swizzled chunk base:
    unsigned short* dst = &sm[wi * WSLOT + (((c >> 3) ^ i) << 3) + (c & 7)];
    dst[(i * 8 + 0) * XSTR] = f2b(v0[0]); dst[(i * 8 + 1) * XSTR] = f2b(v0[1]);
    dst[(i * 8 + 2) * XSTR] = f2b(v0[2]); dst[(i * 8 + 3) * XSTR] = f2b(v0[3]);
    dst[(i * 8 + 4) * XSTR] = f2b(v1[0]); dst[(i * 8 + 5) * XSTR] = f2b(v1[1]);
    dst[(i * 8 + 6) * XSTR] = f2b(v1[2]); dst[(i * 8 + 7) * XSTR] = f2b(v1[3]);
  }
  __syncthreads();  // B0: both xa visible

  unsigned short* xa = sm + wid * WSLOT;                 // [64][XSTR] xsw
  unsigned short* hb = xa + 12800 + hd * 4096;           // 8KB head region
  unsigned short* R0 = hb;            // Q -> Phalf -> AO (4KB, [64][32] swz32)
  unsigned short* R1 = hb + 2048;     // K -> Vt          (4KB)
  const int oQ = hd * 32;

  // ---------------- QKV: Q^T,K^T = mfma(w, x);  V = mfma(x, w) ----------------
  f32x4 accqT[2][4], acckT[2][4], accv[4][2];
#pragma unroll
  for (int m = 0; m < 2; ++m) {
    f32x4 bq4 = *(const f32x4*)&qkv_b[oQ + m * 16 + lg * 4];
    f32x4 bk4 = *(const f32x4*)&qkv_b[192 + oQ + m * 16 + lg * 4];
#pragma unroll
    for (int tn = 0; tn < 4; ++tn) {
      accqT[m][tn] = bq4 * QSCALE;
      acckT[m][tn] = bk4;
    }
  }
#pragma unroll
  for (int nt = 0; nt < 2; ++nt) {
    const float bv = qkv_b[384 + oQ + nt * 16 + l15];
#pragma unroll
    for (int mt = 0; mt < 4; ++mt) accv[mt][nt] = (f32x4){bv, bv, bv, bv};
  }
#pragma unroll
  for (int ks = 0; ks < 6; ++ks) {
    const int k0 = ks * 32 + lg * 8;
    s16x8 bf[4];
#pragma unroll
    for (int tn = 0; tn < 4; ++tn)
      bf[tn] = *(const s16x8*)&xa[xsw(tn * 16 + l15, k0)];
    s16x8 wq[2], wk[2], wvv[2];
#pragma unroll
    for (int m = 0; m < 2; ++m) {
      wq[m] = *(const s16x8*)&qkv_wb[(size_t)(oQ + m * 16 + l15) * 192 + k0];
      wk[m] = *(const s16x8*)&qkv_wb[(size_t)(192 + oQ + m * 16 + l15) * 192 + k0];
      wvv[m] = *(const s16x8*)&qkv_wb[(size_t)(384 + oQ + m * 16 + l15) * 192 + k0];
    }
#pragma unroll
    for (int m = 0; m < 2; ++m)
#pragma unroll
      for (int tn = 0; tn < 4; ++tn) {
        accqT[m][tn] = MFMA(wq[m], bf[tn], accqT[m][tn]);
        acckT[m][tn] = MFMA(wk[m], bf[tn], acckT[m][tn]);
      }
#pragma unroll
    for (int mt = 0; mt < 4; ++mt)
#pragma unroll
      for (int nt = 0; nt < 2; ++nt)
        accv[mt][nt] = MFMA(bf[mt], wvv[nt], accv[mt][nt]);
  }
  // Q,K stores: C[d][t] regs run along d -> u16x4 into row-major [t][d]
#pragma unroll
  for (int m = 0; m < 2; ++m)
#pragma unroll
    for (int tn = 0; tn < 4; ++tn) {
      const int t = tn * 16 + l15, d0 = m * 16 + lg * 4;
      u16x4 q4, k4;
#pragma unroll
      for (int r = 0; r < 4; ++r) {
        q4[r] = f2b(accqT[m][tn][r]);
        k4[r] = f2b(acckT[m][tn][r]);
      }
      *(u16x4*)&R0[swz32(t, d0)] = q4;
      *(u16x4*)&R1[swz32(t, d0)] = k4;
    }
  // V -> bf16 regs (accv dies)
  u16x4 vreg[4][2];
#pragma unroll
  for (int mt = 0; mt < 4; ++mt)
#pragma unroll
    for (int nt = 0; nt < 2; ++nt) {
      vreg[mt][nt][0] = f2b(accv[mt][nt][0]); vreg[mt][nt][1] = f2b(accv[mt][nt][1]);
      vreg[mt][nt][2] = f2b(accv[mt][nt][2]); vreg[mt][nt][3] = f2b(accv[mt][nt][3]);
    }

  // ---------------- scores^T = mfma(K, Q) + bias ----------------
  const float* bxp = biasx + lane * 64;
  s16x8 kf[4], qf[4];
#pragma unroll
  for (int tm = 0; tm < 4; ++tm)
    kf[tm] = *(const s16x8*)&R1[swz32(tm * 16 + l15, lg * 8)];
#pragma unroll
  for (int tn = 0; tn < 4; ++tn)
    qf[tn] = *(const s16x8*)&R0[swz32(tn * 16 + l15, lg * 8)];
  // Vt over K (after kf reads; in-wave DS order)
#pragma unroll
  for (int mt = 0; mt < 4; ++mt)
#pragma unroll
    for (int nt = 0; nt < 2; ++nt)
      *(u16x4*)&R1[swzV(nt * 16 + l15, mt * 16 + lg * 4)] = vreg[mt][nt];

  f32x4 sc[4][4];
#pragma unroll
  for (int tm = 0; tm < 4; ++tm)
#pragma unroll
    for (int tn = 0; tn < 4; ++tn) {
      f32x4 bfr = *(const f32x4*)&bxp[tm * 16 + tn * 4];
      sc[tm][tn] = MFMA(kf[tm], qf[tn], bfr);
    }
  // softmax over keys: 16 in-lane + shfl_xor 16,32
#pragma unroll
  for (int tn = 0; tn < 4; ++tn) {
    float mx = sc[0][tn][0];
#pragma unroll
    for (int tm = 0; tm < 4; ++tm)
#pragma unroll
      for (int r = 0; r < 4; ++r) mx = fmaxf(mx, sc[tm][tn][r]);
    mx = fmaxf(mx, __shfl_xor(mx, 16));
    mx = fmaxf(mx, __shfl_xor(mx, 32));
    float sum = 0.f;
#pragma unroll
    for (int tm = 0; tm < 4; ++tm)
#pragma unroll
      for (int r = 0; r < 4; ++r) {
        float e = __expf(sc[tm][tn][r] - mx);
        sc[tm][tn][r] = e;
        sum += e;
      }
    sum += __shfl_xor(sum, 16);
    sum += __shfl_xor(sum, 32);
    const float inv = 1.0f / sum;
#pragma unroll
    for (int tm = 0; tm < 4; ++tm)
#pragma unroll
      for (int r = 0; r < 4; ++r) sc[tm][tn][r] *= inv;
  }

  // ---------------- PV as out^T = mfma(Vt, P), P in 4KB halves ----------------
  f32x4 oT[2][4];
#pragma unroll
  for (int m = 0; m < 2; ++m)
#pragma unroll
    for (int tn = 0; tn < 4; ++tn) oT[m][tn] = (f32x4){0.f, 0.f, 0.f, 0.f};
#pragma unroll
  for (int half = 0; half < 2; ++half) {
    // P-half store: C=scores^T[k][q] regs run along k -> u16x4 into [q][k]
#pragma unroll
    for (int tm = 0; tm < 2; ++tm)
#pragma unroll
      for (int tn = 0; tn < 4; ++tn) {
        u16x4 p4;
#pragma unroll
        for (int r = 0; r < 4; ++r) p4[r] = f2b(sc[half * 2 + tm][tn][r]);
        *(u16x4*)&R0[swz32(tn * 16 + l15, tm * 16 + lg * 4)] = p4;
      }
    s16x8 bp[4], av[2];
#pragma unroll
    for (int tn = 0; tn < 4; ++tn)
      bp[tn] = *(const s16x8*)&R0[swz32(tn * 16 + l15, lg * 8)];
#pragma unroll
    for (int m = 0; m < 2; ++m)
      av[m] = *(const s16x8*)&R1[swzV(m * 16 + l15, half * 32 + lg * 8)];
#pragma unroll
    for (int m = 0; m < 2; ++m)
#pragma unroll
      for (int tn = 0; tn < 4; ++tn)
        oT[m][tn] = MFMA(av[m], bp[tn], oT[m][tn]);
  }
  // AO store: C[d][t] -> u16x4 into [t][d]
#pragma unroll
  for (int m = 0; m < 2; ++m)
#pragma unroll
    for (int tn = 0; tn < 4; ++tn) {
      u16x4 a4;
#pragma unroll
      for (int r = 0; r < 4; ++r) a4[r] = f2b(oT[m][tn][r]);
      *(u16x4*)&R0[swz32(tn * 16 + l15, m * 16 + lg * 4)] = a4;
    }
  __syncthreads();  // B2: all heads' AO visible

  // ---------------- proj^T = mfma(Wp, AO) + residual RMW ----------------
  f32x4 pjT[2][4];
#pragma unroll
  for (int m = 0; m < 2; ++m) {
    f32x4 bp4 = *(const f32x4*)&proj_b[oQ + m * 16 + lg * 4];
#pragma unroll
    for (int tn = 0; tn < 4; ++tn) pjT[m][tn] = bp4;
  }
#pragma unroll
  for (int hh = 0; hh < 6; ++hh) {
    const unsigned short* aoh = xa + 12800 + hh * 4096;   // head hh's AO
    s16x8 aa[4];
#pragma unroll
    for (int tn = 0; tn < 4; ++tn)
      aa[tn] = *(const s16x8*)&aoh[swz32(tn * 16 + l15, lg * 8)];
    s16x8 wp[2];
#pragma unroll
    for (int m = 0; m < 2; ++m)
      wp[m] = *(const s16x8*)&proj_wb[(size_t)(oQ + m * 16 + l15) * 192 + hh * 32 + lg * 8];
#pragma unroll
    for (int m = 0; m < 2; ++m)
#pragma unroll
      for (int tn = 0; tn < 4; ++tn)
        pjT[m][tn] = MFMA(wp[m], aa[tn], pjT[m][tn]);
  }
  // y = x + proj: vectorized RMW of wave-private swizzled cells
#pragma unroll
  for (int m = 0; m < 2; ++m)
#pragma unroll
    for (int tn = 0; tn < 4; ++tn) {
      const int t = tn * 16 + l15, o0 = oQ + m * 16 + lg * 4;
      const int ad = xsw(t, o0);
      u16x4 old = *(const u16x4*)&xa[ad];
      u16x4 nw;
#pragma unroll
      for (int r = 0; r < 4; ++r) nw[r] = f2b(pjT[m][tn][r] + b2f(old[r]));
      *(u16x4*)&xa[ad] = nw;
    }
  __syncthreads();  // B3: y complete for both windows
  // coalesced copy both windows' y -> y_win (de-swizzled)
#pragma unroll
  for (int it = 0; it < 4; ++it) {
    int job = tid + 768 * it;
    int wi = job / 1536;
    int j = job - wi * 1536;
    int t = j / 24;
    int seg = j - t * 24;
    unsigned short* ywp = y_win + (size_t)(wins0 + wi) * 12288;
    *(u16x8*)&ywp[(size_t)j * 8] = *(const u16x8*)&sm[wi * WSLOT + xsw(t, seg * 8)];
  }
}

// ---------------------------------------------------------------------------
__global__ __launch_bounds__(256, 4) void mlp_kernel(
    const unsigned short* __restrict__ y_win,
    const unsigned short* __restrict__ w1b, const float* __restrict__ b1,
    const unsigned short* __restrict__ w2b, const float* __restrict__ b2,
    float* __restrict__ out) {
  __shared__ __align__(16) unsigned short sm2[2 * 64 * XSTR];  // y_buf + work_buf
  unsigned short* yb = sm2;
  unsigned short* wk = sm2 + 64 * XSTR;

  const int tid  = threadIdx.x;
  const int lane = tid & 63;
  const int wv   = tid >> 6;      // 0..3
  const int l15  = lane & 15;
  const int lg   = lane >> 4;
  const int win  = ((blockIdx.x & 7) << 8) | (blockIdx.x >> 3);
  const int bb   = win >> 8;
  const int wh   = (win >> 4) & 15;
  const int wwi  = win & 15;

  const unsigned short* ywp = y_win + (size_t)win * 12288;
  // ---- stage y tile (fully coalesced) ----
#pragma unroll
  for (int it = 0; it < 6; ++it) {
    int job = tid + 256 * it;     // 1536
    int t = job / 24;
    int seg = job - t * 24;
    *(u16x8*)&yb[t * XSTR + seg * 8] = *(const u16x8*)&ywp[(size_t)job * 8];
  }
  __syncthreads();  // B0

  // ---- GEMM1 + GLU, one a/b pair at a time (acc peak 32 regs) ----
#pragma unroll
  for (int i = 0; i < 3; ++i) {
    const int na = (3 * wv + i) * 16 + l15;   // a column (0..191)
    const int nb = na + 192;                  // paired b column
    f32x4 aacc[4], bacc[4];
    const float ba = b1[na], bbv = b1[nb];
#pragma unroll
    for (int m = 0; m < 4; ++m) {
      aacc[m] = (f32x4){ba, ba, ba, ba};
      bacc[m] = (f32x4){bbv, bbv, bbv, bbv};
    }
#pragma unroll
    for (int ks = 0; ks < 6; ++ks) {
      const int k0 = ks * 32 + lg * 8;
      s16x8 af[4];
#pragma unroll
      for (int m = 0; m < 4; ++m)
        af[m] = *(const s16x8*)&yb[(m * 16 + l15) * XSTR + k0];
      s16x8 wa = *(const s16x8*)&w1b[(size_t)na * 192 + k0];
      s16x8 wb = *(const s16x8*)&w1b[(size_t)nb * 192 + k0];
#pragma unroll
      for (int m = 0; m < 4; ++m) {
        aacc[m] = MFMA(af[m], wa, aacc[m]);
        bacc[m] = MFMA(af[m], wb, bacc[m]);
      }
    }
#pragma unroll
    for (int m = 0; m < 4; ++m)
#pragma unroll
      for (int r = 0; r < 4; ++r) {
        const float g = aacc[m][r] * (1.0f / (1.0f + __expf(-bacc[m][r])));
        wk[(m * 16 + lg * 4 + r) * XSTR + na] = f2b(g);
      }
  }
  __syncthreads();  // B1: g visible

  // ---- GEMM2: m[t][o] = g . w2^T ----
  int ocol[3];
  f32x4 macc[4][3];
#pragma unroll
  for (int i = 0; i < 3; ++i) {
    ocol[i] = (3 * wv + i) * 16 + l15;
    const float bb2 = b2[ocol[i]];
#pragma unroll
    for (int m = 0; m < 4; ++m) macc[m][i] = (f32x4){bb2, bb2, bb2, bb2};
  }
#pragma unroll
  for (int ks = 0; ks < 6; ++ks) {
    const int k0 = ks * 32 + lg * 8;
    s16x8 gf[4];
#pragma unroll
    for (int m = 0; m < 4; ++m)
      gf[m] = *(const s16x8*)&wk[(m * 16 + l15) * XSTR + k0];
#pragma unroll
    for (int i = 0; i < 3; ++i) {
      s16x8 wf = *(const s16x8*)&w2b[(size_t)ocol[i] * 192 + k0];
#pragma unroll
      for (int m = 0; m < 4; ++m) macc[m][i] = MFMA(gf[m], wf, macc[m][i]);
    }
  }
  __syncthreads();  // B2: all g reads done; m may overwrite wk
#pragma unroll
  for (int m = 0; m < 4; ++m)
#pragma unroll
    for (int i = 0; i < 3; ++i)
#pragma unroll
      for (int r = 0; r < 4; ++r)
        wk[(m * 16 + lg * 4 + r) * XSTR + ocol[i]] = f2b(macc[m][i][r]);
  __syncthreads();  // B3: m visible

  // ---- epilogue: out = y + m, BCHW fp32, 32-B runs ----
  float* obase = out + (size_t)bb * 192 * 16384 + (size_t)(wh * 8) * 128 + wwi * 8;
#pragma unroll
  for (int it = 0; it < 6; ++it) {
    int job = tid + 256 * it;     // job = c + 192*i (c fast -> conflict-free LDS)
    int i = job / 192;
    int c = job - i * 192;
    float vals[8];
#pragma unroll
    for (int j = 0; j < 8; ++j) {
      const int t = i * 8 + j;
      vals[j] = b2f(yb[t * XSTR + c]) + b2f(wk[t * XSTR + c]);
    }
    float* dst = obase + (size_t)c * 16384 + i * 128;
    f32x4 o0 = {vals[0], vals[1], vals[2], vals[3]};
    f32x4 o1 = {vals[4], vals[5], vals[6], vals[7]};
    *(f32x4*)dst = o0;
    *(f32x4*)(dst + 4) = o1;
  }
}

// ---------------------------------------------------------------------------
extern "C" void kernel_launch(void* const* d_in, const int* in_sizes, int n_in,
                              void* d_out, int out_size, void* d_ws, size_t ws_size,
                              hipStream_t stream) {
  (void)in_sizes; (void)n_in; (void)out_size; (void)ws_size;
  const float* x          = (const float*)d_in[0];
  const float* qkv_w      = (const float*)d_in[1];
  const float* qkv_b      = (const float*)d_in[2];
  const float* proj_w     = (const float*)d_in[3];
  const float* proj_b     = (const float*)d_in[4];
  const float* mlp1_w     = (const float*)d_in[5];
  const float* mlp1_b     = (const float*)d_in[6];
  const float* mlp2_w     = (const float*)d_in[7];
  const float* mlp2_b     = (const float*)d_in[8];
  const float* bias_table = (const float*)d_in[9];
  const int*   rel_index  = (const int*)d_in[10];
  float* out = (float*)d_out;

  char* ws = (char*)d_ws;
  unsigned short* qkv_wb  = (unsigned short*)ws + WOFF_QKV;
  unsigned short* proj_wb = (unsigned short*)ws + WOFF_PROJ;
  unsigned short* mlp1_wb = (unsigned short*)ws + WOFF_MLP1;
  unsigned short* mlp2_wb = (unsigned short*)ws + WOFF_MLP2;
  float*          biasx   = (float*)(ws + WOFF_BIASX_BYTES);
  unsigned short* y_win   = (unsigned short*)(ws + WOFF_YWIN_BYTES);

  hipLaunchKernelGGL(prep_kernel, dim3(1024), dim3(256), 0, stream,
                     qkv_w, proj_w, mlp1_w, mlp2_w, bias_table, rel_index,
                     qkv_wb, proj_wb, mlp1_wb, mlp2_wb, biasx);
  hipLaunchKernelGGL(attn_kernel, dim3(1024), dim3(768), 0, stream,
                     x, qkv_wb, qkv_b, proj_wb, proj_b, biasx, y_win);
  hipLaunchKernelGGL(mlp_kernel, dim3(2048), dim3(256), 0, stream,
                     y_win, mlp1_wb, mlp1_b, mlp2_wb, mlp2_b, out);
}